// Round 4
// baseline (846.301 us; speedup 1.0000x reference)
//
#include <hip/hip_runtime.h>
#include <math.h>

#define T      512
#define NBATCH 512
#define IN_DIM 64
#define H      100
#define KP     208          // padded contraction rows per layer input vector
#define PBYTES 832          // KP*4: byte stride between parity buffers

// tanh(a) = 1 - 2/(exp(2a)+1)  -- overflow-safe at both ends.
__device__ __forceinline__ float fast_tanh(float a) {
    float e = __expf(2.0f * a);
    return 1.0f - 2.0f / (e + 1.0f);
}

#define DPPMOV(x, ctrl) __int_as_float(__builtin_amdgcn_update_dpp( \
        0, __float_as_int(x), (ctrl), 0xF, 0xF, true))

// weight element for concatenated row R: rows [0,kA) -> WA, [kA,kA+100) -> WB, else 0
__device__ __forceinline__ float wval(const float* __restrict__ WA,
                                      const float* __restrict__ WB,
                                      int kA, int R, int col) {
    if (R < kA) return WA[R * H + col];
    int rr = R - kA;
    return (rr < H) ? WB[rr * H + col] : 0.f;
}

__device__ __forceinline__ float4 wload4(const float* __restrict__ WA,
                                         const float* __restrict__ WB,
                                         int kA, int R0, int col) {
    return make_float4(wval(WA, WB, kA, R0 + 0, col),
                       wval(WA, WB, kA, R0 + 1, col),
                       wval(WA, WB, kA, R0 + 2, col),
                       wval(WA, WB, kA, R0 + 3, col));
}

// ---------------------------------------------------------------------------
// R1 skeleton + K-split-16 geometry. 512 threads, one batch element.
// Unit = 16 lanes, 8 output cols/unit; 13 L1 units + 13 L2 units (L2 one
// step behind) over waves 0-6; wave 7 = x-prefetch. Per thread: 13 K-floats
// x 8 cols = 104 weight floats (24 float4 + 8 tail scalars), 104 scalar
// fmaf, and only 3 ds_read_b128 + 1 ds_read_b32 per DOT (vs 7 ds-ops in
// R1 -- the LDS pipe was ~half the per-body cost). col(l)=(l&3)|((l>>1)&4);
// reduction = verified DPP pair-merge over lane bits {0,1,3} (quad_perm
// xor1/xor2, row_ror:8) + final xor4 (half_mirror o quad3), zero LDS ops.
// Scalar fmaf only (R2's asm pk_fma forced AGPR<->VGPR copies: regression).
// No xring / shadow / p-union (R3's spill source: WRITE_SIZE 9 MB).
// ---------------------------------------------------------------------------

#define FMA4(r, c, v) { a##c = fmaf((v).x, w##r##_##c.x, a##c); \
                        a##c = fmaf((v).y, w##r##_##c.y, a##c); \
                        a##c = fmaf((v).z, w##r##_##c.z, a##c); \
                        a##c = fmaf((v).w, w##r##_##c.w, a##c); }
#define FROUND(r, v) FMA4(r,0,v) FMA4(r,1,v) FMA4(r,2,v) FMA4(r,3,v) \
                     FMA4(r,4,v) FMA4(r,5,v) FMA4(r,6,v) FMA4(r,7,v)

#define WDECL(c) float4 w0_##c = {0,0,0,0}, w1_##c = {0,0,0,0}, w2_##c = {0,0,0,0};
#define WLOADC(c) { w0_##c = wload4(WA, WB, kA,       4*s, cc##c); \
                    w1_##c = wload4(WA, WB, kA,  64 + 4*s, cc##c); \
                    w2_##c = wload4(WA, WB, kA, 128 + 4*s, cc##c); }
#define WCOLS(X) X(0) X(1) X(2) X(3) X(4) X(5) X(6) X(7)

#define DOTCORE(P, hv) {                                                   \
    const float4 v0_ = *(const float4*)(rb + (P));                         \
    const float4 v1_ = *(const float4*)(rb + (P) + 256);                   \
    const float4 v2_ = *(const float4*)(rb + (P) + 512);                   \
    float a0=0.f,a1=0.f,a2=0.f,a3=0.f,a4=0.f,a5=0.f,a6=0.f,a7=0.f;         \
    FROUND(0, v0_) FROUND(1, v1_) FROUND(2, v2_)                           \
    if (hasTail) {                                                         \
        const float vt_ = *(const float*)(tb + (P));                       \
        a0 = fmaf(vt_, wt0, a0); a1 = fmaf(vt_, wt1, a1);                  \
        a2 = fmaf(vt_, wt2, a2); a3 = fmaf(vt_, wt3, a3);                  \
        a4 = fmaf(vt_, wt4, a4); a5 = fmaf(vt_, wt5, a5);                  \
        a6 = fmaf(vt_, wt6, a6); a7 = fmaf(vt_, wt7, a7);                  \
    }                                                                      \
    /* merge col bit0 <-> lane bit0 (quad_perm xor1) */                    \
    float u0_ = (q0 ? a1 : a0) + DPPMOV(q0 ? a0 : a1, 0xB1);               \
    float u1_ = (q0 ? a3 : a2) + DPPMOV(q0 ? a2 : a3, 0xB1);               \
    float u2_ = (q0 ? a5 : a4) + DPPMOV(q0 ? a4 : a5, 0xB1);               \
    float u3_ = (q0 ? a7 : a6) + DPPMOV(q0 ? a6 : a7, 0xB1);               \
    /* merge col bit1 <-> lane bit1 (quad_perm xor2) */                    \
    float r0_ = (q1 ? u1_ : u0_) + DPPMOV(q1 ? u0_ : u1_, 0x4E);           \
    float r1_ = (q1 ? u3_ : u2_) + DPPMOV(q1 ? u2_ : u3_, 0x4E);           \
    /* merge col bit2 <-> lane bit3 (row_ror:8 = xor8 in 16-lane row) */   \
    float z_  = (q3 ? r1_ : r0_) + DPPMOV(q3 ? r0_ : r1_, 0x128);          \
    /* sum over lane bit2, same col: half_mirror(^7) o quad3(^3) = ^4 */   \
    z_ += DPPMOV(DPPMOV(z_, 0x141), 0x1B);                                 \
    hv = fast_tanh(z_ + bj); }

__global__ __launch_bounds__(512, 4)
void drnn_kernel(const float* __restrict__ x,
                 const float* __restrict__ W1x, const float* __restrict__ W1h,
                 const float* __restrict__ b1,
                 const float* __restrict__ W2x, const float* __restrict__ W2h,
                 const float* __restrict__ b2,
                 const float* __restrict__ Wo,  const float* __restrict__ bo,
                 float* __restrict__ out)
{
    // in1: [x_t (64) | h1 (100) | pad->208]; in2: [h1 (100) | h2 (100) | pad->208]
    __shared__ __align__(16) float in1[2][KP];
    __shared__ __align__(16) float in2[2][KP];

    const int tid  = threadIdx.x;
    const int b    = blockIdx.x;
    const int lane = tid & 63;
    const int wv   = tid >> 6;
    const int s    = lane & 15;                  // K-slice within 16-lane unit
    const int unit = wv * 4 + (lane >> 4);       // 0..31
    const bool active = (unit < 26);             // 13 L1 + 13 L2 units
    const bool isL1   = (unit < 13);
    const bool isXL   = (wv == 7);               // x-prefetch wave
    const bool hasTail = (wv >= 3);              // waves 0-2 pure-L1: tail all-zero

    const float* __restrict__ xrow = x + (size_t)b * T * IN_DIM;

    // ---- zero-init LDS (pads must stay 0; h(-1)=0; h2(-1) slot stays 0) ----
    for (int k = tid; k < 2 * KP; k += 512) {
        (&in1[0][0])[k] = 0.f;
        (&in2[0][0])[k] = 0.f;
    }
    if (tid < IN_DIM) in1[0][tid] = xrow[tid];   // x(0)

    const float* __restrict__ WA = isL1 ? W1x : W2x;
    const float* __restrict__ WB = isL1 ? W1h : W2h;
    const int kA = isL1 ? IN_DIM : H;            // rows [0,kA)->WA, [kA,kA+100)->WB
    const int ul = isL1 ? unit : unit - 13;
    const int j  = 8 * ((ul >= 0 && ul < 13) ? ul : 0);     // col base <= 96
    const int colof = (lane & 3) | ((lane >> 1) & 4);       // col via lane bits {0,1,3}
    const int n  = j + colof;                               // col this lane finalizes
    const int nc = (n < H) ? n : H - 1;
    const float bj = active ? (isL1 ? b1 : b2)[nc] : 0.f;
    const int cc0=(j+0<H)?j+0:H-1, cc1=(j+1<H)?j+1:H-1, cc2=(j+2<H)?j+2:H-1, cc3=(j+3<H)?j+3:H-1;
    const int cc4=(j+4<H)?j+4:H-1, cc5=(j+5<H)?j+5:H-1, cc6=(j+6<H)?j+6:H-1, cc7=(j+7<H)?j+7:H-1;

    const bool q0 = (lane & 1) != 0;
    const bool q1 = (lane & 2) != 0;
    const bool q3 = (lane & 8) != 0;

    // ---- 104 weight floats: 24 float4 (rounds 0-2) + 8 tail scalars ----
    WCOLS(WDECL)
    float wt0=0.f,wt1=0.f,wt2=0.f,wt3=0.f,wt4=0.f,wt5=0.f,wt6=0.f,wt7=0.f;
    if (active) {
        WCOLS(WLOADC)
        const int Rt = 192 + s;                  // all-zero for L1 (Rt >= kA+H)
        wt0 = wval(WA,WB,kA,Rt,cc0); wt1 = wval(WA,WB,kA,Rt,cc1);
        wt2 = wval(WA,WB,kA,Rt,cc2); wt3 = wval(WA,WB,kA,Rt,cc3);
        wt4 = wval(WA,WB,kA,Rt,cc4); wt5 = wval(WA,WB,kA,Rt,cc5);
        wt6 = wval(WA,WB,kA,Rt,cc6); wt7 = wval(WA,WB,kA,Rt,cc7);
    }

    // ---- per-lane LDS pointers; odd parity via +PBYTES immediate ----
    const char* lb = (const char*)(isL1 ? &in1[0][0] : &in2[0][0]);
    const char* rb = lb + 16 * s;                // rounds at +0 / +256 / +512
    const char* tb = lb + 768 + 4 * s;           // tail row 192+s

    // parity-0 store slot + write-enable; duplicate pair (lane^4) splits
    // L1's two stores; L2 dupes masked.
    char* st; bool dow;
    if (isL1) { st = (char*)((lane & 4) ? &in2[0][n] : &in1[0][64 + n]);
                dow = active && (n < H); }
    else      { st = (char*)&in2[0][100 + n];
                dow = active && (n < H) && !(lane & 4); }

    // ---- x register pipeline (wave 7), two steps ahead ----
    char* xw = (char*)&in1[0][lane];
    float xr0 = 0.f, xr1 = 0.f;
    if (isXL) {
        xr0 = xrow[1 * IN_DIM + lane];           // x(1)
        xr1 = xrow[2 * IN_DIM + lane];           // x(2)
    }

    __syncthreads();

    // Body i: L1 computes h1(i); L2 computes h2(i-1). Wave 7 stages x(i+1).
    #pragma unroll 1
    for (int i = 0; i < T; i += 2) {
        // ---- even body: read parity 0, write parity 1 ----
        if (active) {
            float hv; DOTCORE(0, hv)
            if (dow && (isL1 || i > 0)) *(float*)(st + PBYTES) = hv;  // skip bogus h2(-1)
        } else if (isXL) {
            *(float*)(xw + PBYTES) = xr0;        // x(i+1)
            xr0 = xr1;
            if (i + 3 < T) xr1 = xrow[(size_t)(i + 3) * IN_DIM + lane];
        }
        __syncthreads();
        // ---- odd body: read parity 1, write parity 0 ----
        if (active) {
            float hv; DOTCORE(PBYTES, hv)
            if (dow) *(float*)st = hv;
        } else if (isXL) {
            *(float*)xw = xr0;                   // x(i+2)
            xr0 = xr1;
            if (i + 4 < T) xr1 = xrow[(size_t)(i + 4) * IN_DIM + lane];
        }
        __syncthreads();
    }

    // ---- tail body (parity 0): only L2, computes h2(T-1) ----
    if (active && !isL1) {
        float hv; DOTCORE(0, hv)
        if (dow) *(float*)(st + PBYTES) = hv;    // -> in2[1][100..]
    }
    __syncthreads();

    // ---- epilogue: h1(T-1) in in1[0][64..], h2(T-1) in in2[1][100..] ----
    if (tid < H)
        out[NBATCH + (size_t)b * H + tid] = in1[0][64 + tid];
    if (tid < H)
        out[NBATCH + (size_t)NBATCH * H + (size_t)b * H + tid] = in2[1][100 + tid];

    // out[b] = h2_T . Wo + bo  (wave-0 shuffle reduction)
    if (tid < 64) {
        float v = in2[1][100 + tid] * Wo[tid];
        if (tid + 64 < H) v += in2[1][100 + 64 + tid] * Wo[tid + 64];
        #pragma unroll
        for (int off = 32; off >= 1; off >>= 1) v += __shfl_down(v, off);
        if (tid == 0) out[b] = v + bo[0];
    }
}

extern "C" void kernel_launch(void* const* d_in, const int* in_sizes, int n_in,
                              void* d_out, int out_size, void* d_ws, size_t ws_size,
                              hipStream_t stream) {
    const float* x   = (const float*)d_in[0];
    const float* W1x = (const float*)d_in[1];
    const float* W1h = (const float*)d_in[2];
    const float* b1  = (const float*)d_in[3];
    const float* W2x = (const float*)d_in[4];
    const float* W2h = (const float*)d_in[5];
    const float* b2  = (const float*)d_in[6];
    const float* Wo  = (const float*)d_in[7];
    const float* bo  = (const float*)d_in[8];
    float* out = (float*)d_out;

    drnn_kernel<<<NBATCH, 512, 0, stream>>>(x, W1x, W1h, b1, W2x, W2h, b2,
                                            Wo, bo, out);
}

// Round 5
// 621.113 us; speedup vs baseline: 1.3626x; 1.3626x over previous
//
#include <hip/hip_runtime.h>
#include <math.h>

#define T      512
#define NBATCH 512
#define IN_DIM 64
#define H      100
#define KP     208          // padded contraction rows per layer input vector
#define PBYTES 832          // KP*4: byte stride between parity buffers

// tanh(a) = 1 - 2/(exp(2a)+1)  -- overflow-safe at both ends.
__device__ __forceinline__ float fast_tanh(float a) {
    float e = __expf(2.0f * a);
    return 1.0f - 2.0f / (e + 1.0f);
}

#define DPPMOV(x, ctrl) __int_as_float(__builtin_amdgcn_update_dpp( \
        0, __float_as_int(x), (ctrl), 0xF, 0xF, true))

// weight element, 0 if col out of range or row in pad region.
// concat rows: [0,kA) -> WA, [kA,kA+100) -> WB, else 0.
__device__ __forceinline__ float wvalc(const float* __restrict__ WA,
                                       const float* __restrict__ WB,
                                       int kA, int R, int col) {
    if (col >= H) return 0.f;
    if (R < kA) return WA[R * H + col];
    int rr = R - kA;
    return (rr < H) ? WB[rr * H + col] : 0.f;
}

__device__ __forceinline__ float4 wload4c(const float* __restrict__ WA,
                                          const float* __restrict__ WB,
                                          int kA, int R0, int col) {
    return make_float4(wvalc(WA, WB, kA, R0 + 0, col),
                       wvalc(WA, WB, kA, R0 + 1, col),
                       wvalc(WA, WB, kA, R0 + 2, col),
                       wvalc(WA, WB, kA, R0 + 3, col));
}

// ---------------------------------------------------------------------------
// 256-thread block (the 256-reg/thread regime: __launch_bounds__(256,2) --
// R1-R4 showed the 512-thread/128-reg regime spills as soon as live set
// exceeds ~128; WRITE_SIZE marched 2.5->12 MB). One batch element per block.
// Unit = 16 lanes; 16 cols/unit. Units 0-6 = L1, 7-13 = L2 (one step
// behind), 14/15 = x-prefetch. Per thread: 13 K-floats x 16 cols = 208
// weight floats (48 float4 + 16 tail scalars), 208 fmaf, and only
// 3 ds_read_b128 + 1 ds_read_b32 per DOT (R0 paid 13 b128).
// Reduction: XOR-indexed butterfly. acc k holds col j + (k ^ cl) where
// cl = (l&3)|((l>>1)&4)|((l&4)<<1). Every level is select-free
// a_even + dpp(a_odd): xor1 (quad_perm 0xB1) merges k-bit0<->lane-bit0,
// xor2 (0x4E) k-bit1<->lane-bit1, xor8 (row_ror:8) k-bit2<->lane-bit3,
// xor4 (half_mirror o quad3 = ^7 o ^3) k-bit3<->lane-bit2. Lane l ends
// holding col j + cl. All-DPP, zero LDS traffic, no cndmasks.
// ---------------------------------------------------------------------------

#define K16(X) X(0) X(1) X(2) X(3) X(4) X(5) X(6) X(7) \
               X(8) X(9) X(10) X(11) X(12) X(13) X(14) X(15)

#define WDECL(k) float4 w0_##k={0,0,0,0}, w1_##k={0,0,0,0}, w2_##k={0,0,0,0}; \
                 float wt##k = 0.f;
#define WLOAD(k) { const int ck_ = j + ((k) ^ cl);                \
    w0_##k = wload4c(WA, WB, kA,        4*l, ck_);                \
    w1_##k = wload4c(WA, WB, kA,  64 + 4*l, ck_);                 \
    w2_##k = wload4c(WA, WB, kA, 128 + 4*l, ck_);                 \
    wt##k  = wvalc (WA, WB, kA, 192 + l,   ck_); }

#define ADECL(k) float a##k = 0.f;
#define FR0(k) { a##k = fmaf(v0_.x, w0_##k.x, a##k); a##k = fmaf(v0_.y, w0_##k.y, a##k); \
                 a##k = fmaf(v0_.z, w0_##k.z, a##k); a##k = fmaf(v0_.w, w0_##k.w, a##k); }
#define FR1(k) { a##k = fmaf(v1_.x, w1_##k.x, a##k); a##k = fmaf(v1_.y, w1_##k.y, a##k); \
                 a##k = fmaf(v1_.z, w1_##k.z, a##k); a##k = fmaf(v1_.w, w1_##k.w, a##k); }
#define FR2(k) { a##k = fmaf(v2_.x, w2_##k.x, a##k); a##k = fmaf(v2_.y, w2_##k.y, a##k); \
                 a##k = fmaf(v2_.z, w2_##k.z, a##k); a##k = fmaf(v2_.w, w2_##k.w, a##k); }
#define FT(k)  { a##k = fmaf(vt_, wt##k, a##k); }

#define DOTCORE(P, hv) {                                                  \
    const float4 v0_ = *(const float4*)(rb + (P));                        \
    const float4 v1_ = *(const float4*)(rb + (P) + 256);                  \
    const float4 v2_ = *(const float4*)(rb + (P) + 512);                  \
    const float  vt_ = *(const float*)(tb + (P));                         \
    K16(ADECL)                                                            \
    K16(FR0) K16(FR1) K16(FR2)                                            \
    if (hasTail) { K16(FT) }                                              \
    float u0_ = a0  + DPPMOV(a1,  0xB1);                                  \
    float u1_ = a2  + DPPMOV(a3,  0xB1);                                  \
    float u2_ = a4  + DPPMOV(a5,  0xB1);                                  \
    float u3_ = a6  + DPPMOV(a7,  0xB1);                                  \
    float u4_ = a8  + DPPMOV(a9,  0xB1);                                  \
    float u5_ = a10 + DPPMOV(a11, 0xB1);                                  \
    float u6_ = a12 + DPPMOV(a13, 0xB1);                                  \
    float u7_ = a14 + DPPMOV(a15, 0xB1);                                  \
    float r0_ = u0_ + DPPMOV(u1_, 0x4E);                                  \
    float r1_ = u2_ + DPPMOV(u3_, 0x4E);                                  \
    float r2_ = u4_ + DPPMOV(u5_, 0x4E);                                  \
    float r3_ = u6_ + DPPMOV(u7_, 0x4E);                                  \
    float z0_ = r0_ + DPPMOV(r1_, 0x128);                                 \
    float z1_ = r2_ + DPPMOV(r3_, 0x128);                                 \
    float zz_ = z0_ + DPPMOV(DPPMOV(z1_, 0x141), 0x1B);                   \
    hv = fast_tanh(zz_ + bj); }

__global__ __launch_bounds__(256, 2)
void drnn_kernel(const float* __restrict__ x,
                 const float* __restrict__ W1x, const float* __restrict__ W1h,
                 const float* __restrict__ b1,
                 const float* __restrict__ W2x, const float* __restrict__ W2h,
                 const float* __restrict__ b2,
                 const float* __restrict__ Wo,  const float* __restrict__ bo,
                 float* __restrict__ out)
{
    // in1: [x_t (64) | h1 (100) | pad->208]; in2: [h1 (100) | h2 (100) | pad->208]
    __shared__ __align__(16) float in1[2][KP];
    __shared__ __align__(16) float in2[2][KP];

    const int tid  = threadIdx.x;
    const int b    = blockIdx.x;
    const int wv   = tid >> 6;
    const int l    = tid & 15;                   // K-slice within 16-lane unit
    const int unit = tid >> 4;                   // 0..15
    const bool comp  = (unit < 14);              // 7 L1 + 7 L2 units
    const bool isL1  = (unit < 7);
    const bool isX14 = (unit == 14);             // even-body x stage
    const bool isX15 = (unit == 15);             // odd-body x stage
    const bool hasTail = (wv >= 1);              // wave0 pure-L1: tail all-zero

    const float* __restrict__ xrow = x + (size_t)b * T * IN_DIM;

    // ---- zero-init LDS (pads must stay 0; h(-1)=0; h2(-1) slot stays 0) ----
    for (int k = tid; k < 2 * KP; k += 256) {
        (&in1[0][0])[k] = 0.f;
        (&in2[0][0])[k] = 0.f;
    }
    if (tid < IN_DIM) in1[0][tid] = xrow[tid];   // x(0)

    const float* __restrict__ WA = isL1 ? W1x : W2x;
    const float* __restrict__ WB = isL1 ? W1h : W2h;
    const int kA = isL1 ? IN_DIM : H;            // rows [0,kA)->WA, [kA,kA+100)->WB
    const int ul = isL1 ? unit : unit - 7;
    const int j  = 16 * ((ul < 7) ? ul : 0);     // col base <= 96
    const int cl = (l & 3) | ((l >> 1) & 4) | ((l & 4) << 1);  // final col-in-unit
    const int n  = j + cl;                       // col this lane finalizes (0..111)
    const bool stok = (n < H);
    const int nc = stok ? n : H - 1;
    const float bj = comp ? (isL1 ? b1 : b2)[nc] : 0.f;

    // ---- 208 weight floats: 48 float4 (rounds 0-2) + 16 tail scalars ----
    K16(WDECL)
    if (comp) { K16(WLOAD) }

    // ---- per-lane LDS pointers; odd parity via +PBYTES immediate ----
    const char* lb = (const char*)(isL1 ? &in1[0][0] : &in2[0][0]);
    const char* rb = lb + 16 * l;                // rounds at +0 / +256 / +512
    const char* tb = lb + 768 + 4 * l;           // tail row 192+l

    // parity-0 store slots (parity1 = +PBYTES)
    char* stA = (char*)&in1[0][64 + nc];         // L1: h1 recurrent slot
    char* stB = (char*)&in2[0][nc];              // L1: h1 -> L2's input slot
    char* stC = (char*)&in2[0][100 + nc];        // L2: h2 recurrent slot

    // ---- x float4 pipeline: unit14 stages even bodies, unit15 odd ----
    float4 xr = {0.f, 0.f, 0.f, 0.f};
    if (isX14) xr = *(const float4*)(xrow + 1 * IN_DIM + 4 * l);   // x(1)
    if (isX15) xr = *(const float4*)(xrow + 2 * IN_DIM + 4 * l);   // x(2)
    char* xw14 = (char*)&in1[1][4 * l];
    char* xw15 = (char*)&in1[0][4 * l];

    __syncthreads();

    // Body i: L1 computes h1(i); L2 computes h2(i-1).
    #pragma unroll 1
    for (int i = 0; i < T; i += 2) {
        // ---- even body: read parity 0, write parity 1 ----
        if (comp) {
            float hv; DOTCORE(0, hv)
            if (isL1) {
                if (stok) { *(float*)(stA + PBYTES) = hv;
                            *(float*)(stB + PBYTES) = hv; }
            } else if (stok && i > 0) {          // skip bogus h2(-1)
                *(float*)(stC + PBYTES) = hv;
            }
        } else if (isX14) {
            *(float4*)xw14 = xr;                 // x(i+1) -> parity 1
            if (i + 3 < T) xr = *(const float4*)(xrow + (size_t)(i + 3) * IN_DIM + 4 * l);
        }
        __syncthreads();
        // ---- odd body: read parity 1, write parity 0 ----
        if (comp) {
            float hv; DOTCORE(PBYTES, hv)
            if (isL1) {
                if (stok) { *(float*)stA = hv; *(float*)stB = hv; }
            } else if (stok) {
                *(float*)stC = hv;
            }
        } else if (isX15) {
            *(float4*)xw15 = xr;                 // x(i+2) -> parity 0
            if (i + 4 < T) xr = *(const float4*)(xrow + (size_t)(i + 4) * IN_DIM + 4 * l);
        }
        __syncthreads();
    }

    // ---- tail body (parity 0): only L2, computes h2(T-1) ----
    if (comp && !isL1) {
        float hv; DOTCORE(0, hv)
        if (stok) *(float*)(stC + PBYTES) = hv;  // -> in2[1][100..]
    }
    __syncthreads();

    // ---- epilogue: h1(T-1) in in1[0][64..], h2(T-1) in in2[1][100..] ----
    if (tid < H)
        out[NBATCH + (size_t)b * H + tid] = in1[0][64 + tid];
    if (tid < H)
        out[NBATCH + (size_t)NBATCH * H + (size_t)b * H + tid] = in2[1][100 + tid];

    // out[b] = h2_T . Wo + bo  (wave-0 shuffle reduction)
    if (tid < 64) {
        float v = in2[1][100 + tid] * Wo[tid];
        if (tid + 64 < H) v += in2[1][100 + 64 + tid] * Wo[tid + 64];
        #pragma unroll
        for (int off = 32; off >= 1; off >>= 1) v += __shfl_down(v, off);
        if (tid == 0) out[b] = v + bo[0];
    }
}

extern "C" void kernel_launch(void* const* d_in, const int* in_sizes, int n_in,
                              void* d_out, int out_size, void* d_ws, size_t ws_size,
                              hipStream_t stream) {
    const float* x   = (const float*)d_in[0];
    const float* W1x = (const float*)d_in[1];
    const float* W1h = (const float*)d_in[2];
    const float* b1  = (const float*)d_in[3];
    const float* W2x = (const float*)d_in[4];
    const float* W2h = (const float*)d_in[5];
    const float* b2  = (const float*)d_in[6];
    const float* Wo  = (const float*)d_in[7];
    const float* bo  = (const float*)d_in[8];
    float* out = (float*)d_out;

    drnn_kernel<<<NBATCH, 256, 0, stream>>>(x, W1x, W1h, b1, W2x, W2h, b2,
                                            Wo, bo, out);
}